// Round 8
// baseline (406.430 us; speedup 1.0000x reference)
//
#include <hip/hip_runtime.h>
#include <hip/hip_bf16.h>
#include <stdint.h>
#include <stddef.h>

// QuestionSpecificMLP R13:
//  R12 analysis: harness poison-fill of ws = 119 us fixed floor (in timed
//  window, top-5 forever). Trunk is LDS-read-bound: 8 waves x 12 ds_read_b128
//  per step each feeding 1 MFMA = 96 KB LDS reads/step/block (~1150 cyc).
//  trunk_k4: BM2=256, 32 rows/wave -> each B-read feeds 2 MFMA (halves LDS
//  bytes/FLOP); x staged via global_load_lds with XOR-swizzled SOURCE
//  (linear dest, swizzled read - guide rule #21) -> x reads fully coalesced
//  128 B/row segments; xS dbuf overlaid on hS (dead until epilogue-1).
//  1 block/CU x 8 waves; per-step floor = 32 KB x-tile @ HBM (~3200 cyc) >
//  LDS (~2600) > MFMA (~920) -> throughput-bound, not latency-bound.
//  head_k / prep / ws-gate / fallback: byte-stable from R12.

typedef short s8v __attribute__((ext_vector_type(8)));   // 8 bf16 (4 VGPRs)
typedef float f4v __attribute__((ext_vector_type(4)));   // MFMA acc
typedef float f4a __attribute__((ext_vector_type(4), aligned(4)));  // 4B-aligned float4

typedef const void __attribute__((address_space(1))) *gas1_t;
typedef void __attribute__((address_space(3))) *las3_t;

namespace {
constexpr int kDin = 385;
constexpr int kDh  = 192;
constexpr int kQ   = 1000;
constexpr int kC   = 16;
constexpr int BM   = 64;          // head_k / fallback row tile
constexpr int BM2  = 256;         // trunk_k4 row tile
constexpr int NT   = 512;
constexpr int NK1  = 13;          // ceil(385/32), zero-padded
constexpr int NK2  = 6;           // 192/32
constexpr int CHUNK = 12 * 64 * 8;   // 6144 bf16 (12288 B) per swizzled k-chunk
constexpr int H2   = 200;         // bf16 stride for h / feat rows in LDS

// ---- fallback (small ws) layout: identical to proven R8 ------------------
constexpr size_t WS_W1   = 0;        // 159744
constexpr size_t WS_W2   = 163840;   // 73728 -> ends 237568
constexpr size_t WS_HIST = 245760;   // 2048*4 counts
constexpr size_t WS_CUR  = 253952;   // 2048*4 rank counters
constexpr size_t WS_PERM = 262144;   // 131072*4 -> ends at 768 KB

// ---- big layout (feat staged in ws) --------------------------------------
constexpr size_t WB_FEAT = 0;                         // 131072*192*2 = 50331648
constexpr size_t WB_W1   = 50331648;                  // 159744
constexpr size_t WB_W2   = WB_W1 + 159744;            // 50491392, 73728
constexpr size_t WB_HIST = WB_W2 + 73728;             // 50565120, 8192
constexpr size_t WB_CUR  = WB_HIST + 8192;            // 50573312, 8192
constexpr size_t WB_PERM = WB_CUR + 8192;             // 50581504, 524288
constexpr size_t WB_NEED = WB_PERM + 524288;          // 51105792
constexpr size_t WS_SANE_MAX = (1ull << 36);          // 64 GB: reject garbage
}

__device__ __forceinline__ unsigned short f2bf(float f) {
  unsigned int u = __float_as_uint(f);
  u = u + 0x7fffu + ((u >> 16) & 1u);       // RNE (non-NaN inputs)
  return (unsigned short)(u >> 16);
}

// packed pair: low 16 = bf16(lo), high 16 = bf16(hi); lowers to v_cvt_pk_bf16_f32
__device__ __forceinline__ unsigned int pk2(float lo, float hi) {
  union { __hip_bfloat162 h2; unsigned int u; } cv;
  cv.h2 = __float22bfloat162_rn(make_float2(lo, hi));
  return cv.u;
}

union s8u { s8v s; unsigned int u[4]; };

// ---- combined prep: histogram + both weight swizzles ---------------------
__device__ __forceinline__ void swz_one(const float* W, int K, int i,
                                        unsigned short* out) {
  int k = i / kDh;
  int c = i - k * kDh;
  float v = (k < K) ? W[(size_t)k * kDh + c] : 0.f;
  int oi = (k >> 5) * CHUNK + (((c >> 4) * 64 + ((k >> 3) & 3) * 16 + (c & 15)) << 3)
         + (k & 7);
  out[oi] = f2bf(v);
}

__global__ void combo_prep(const int* __restrict__ qid, const int* __restrict__ isc,
                           int B, int nbH,
                           const float* __restrict__ W1, const float* __restrict__ W2,
                           int* __restrict__ hist,
                           unsigned short* __restrict__ W1sw,
                           unsigned short* __restrict__ W2sw) {
  int bid = blockIdx.x;
  if (bid < nbH) {
    int i = bid * 256 + threadIdx.x;
    if (i < B) atomicAdd(&hist[qid[i] + isc[i] * kQ], 1);
  } else if (bid < nbH + 312) {                       // 312*256 = 416*192
    swz_one(W1, kDin, (bid - nbH) * 256 + threadIdx.x, W1sw);
  } else {                                            // 144*256 = 192*192
    swz_one(W2, kDh, (bid - nbH - 312) * 256 + threadIdx.x, W2sw);
  }
}

// ---- scan folded into scatter: each block recomputes the 2048-bin scan ----
__global__ __launch_bounds__(256)
void scatter2(const int* __restrict__ qid, const int* __restrict__ isc, int B,
              const int* __restrict__ hist, int* __restrict__ rank_ctr,
              int* __restrict__ perm) {
  __shared__ int sh[2048];
  __shared__ int ssum[256];
  int t = threadIdx.x;
  int4 a = ((const int4*)hist)[t * 2];
  int4 b = ((const int4*)hist)[t * 2 + 1];
  int s1 = a.x + a.y, s2 = s1 + a.z, s3 = s2 + a.w;
  int s4 = s3 + b.x, s5 = s4 + b.y, s6 = s5 + b.z, s7 = s6 + b.w;
  ssum[t] = s7;
  __syncthreads();
  #pragma unroll
  for (int d = 1; d < 256; d <<= 1) {
    int xv = (t >= d) ? ssum[t - d] : 0;
    __syncthreads();
    ssum[t] += xv;
    __syncthreads();
  }
  int base = ssum[t] - s7;                 // exclusive prefix over 8-bin groups
  sh[t * 8 + 0] = base;
  sh[t * 8 + 1] = base + a.x;
  sh[t * 8 + 2] = base + s1;
  sh[t * 8 + 3] = base + s2;
  sh[t * 8 + 4] = base + s3;
  sh[t * 8 + 5] = base + s4;
  sh[t * 8 + 6] = base + s5;
  sh[t * 8 + 7] = base + s6;
  __syncthreads();
  int i = blockIdx.x * 256 + t;
  if (i < B) {
    int h = qid[i] + isc[i] * kQ;
    int pos = sh[h] + atomicAdd(&rank_ctr[h], 1);
    perm[pos] = i;
  }
}

// ---- async weight chunk staging: linear LDS, wave-uniform base -----------
__device__ __forceinline__ void stage_w(const unsigned short* gsrc,
                                        unsigned short* lbase, int tid) {
  const char* g = (const char*)gsrc + (size_t)tid * 16;
  char* l = (char*)lbase + ((tid >> 6) << 10);
  __builtin_amdgcn_global_load_lds((gas1_t)g, (las3_t)l, 16, 0, 0);
  if (tid < 256)
    __builtin_amdgcn_global_load_lds((gas1_t)(g + 8192), (las3_t)(l + 8192),
                                     16, 0, 0);
}

// ---- x tile staging: [256 rows][128 B], XOR-swizzled source --------------
// lds[row][j] (16B units, j=0..7) holds x[row][ j ^ (row&7) ].
// Dest is linear (gload_lds requirement); source stays coalesced per row
// (8 lanes cover a permuted contiguous 128 B). Read side applies same XOR.
__device__ __forceinline__ void stage_x(const float* xg, int row0, int g,
                                        unsigned short* xbuf, int tid) {
  #pragma unroll
  for (int t = 0; t < 4; ++t) {
    int s = tid + t * 512;                 // slot: row = s>>3, unit j = s&7
    int r = s >> 3;
    int j = s & 7;
    const float* src = xg + (size_t)(row0 + r) * kDin + g * 32
                     + ((j ^ (r & 7)) << 2);
    char* l = (char*)xbuf + ((tid >> 6) << 10) + t * 8192;  // dest byte = s*16
    __builtin_amdgcn_global_load_lds((gas1_t)src, (las3_t)l, 16, 0, 0);
  }
}

// ===========================================================================
//  BIG PATH trunk: BM2=256, 32 rows/wave (2x B-reuse), x through LDS
// ===========================================================================
__global__ __launch_bounds__(NT, 2)
void trunk_k4(const float* __restrict__ x,
              const float* __restrict__ b1,
              const float* __restrict__ b2,
              const unsigned short* __restrict__ W1sw,
              const unsigned short* __restrict__ W2sw,
              unsigned short* __restrict__ featG) {
  __shared__ __align__(16) unsigned short hS[BM2 * H2];    // 102400 B
  __shared__ __align__(16) unsigned short bS[2 * CHUNK];   // 24576 B dbuf
  // xS double buffer overlays hS bytes [0, 65536): dead until epilogue-1.

  const int tid  = threadIdx.x;
  const int lane = tid & 63, wid = tid >> 6;   // wid 0..7
  const int m = lane & 15, quad = lane >> 4;
  const int w32 = wid * 32;                    // wave's private 32-row group
  const int row0 = blockIdx.x * BM2;
  const int z = m & 7;
  const int u0 = (((quad << 1) ^ z) << 4);     // swizzled byte off of unit 2q

  // prologue: weights chunk0 -> bS buf0; x step0 -> xS buf0
  stage_w(W1sw, bS, tid);
  stage_x(x, row0, 0, (unsigned short*)hS, tid);

  f4v accA[12], accB[12];
  #pragma unroll
  for (int t = 0; t < 12; ++t) {
    accA[t] = (f4v){0.f, 0.f, 0.f, 0.f};
    accB[t] = (f4v){0.f, 0.f, 0.f, 0.f};
  }
  float tl0 = 0.f, tl1 = 0.f;
  __syncthreads();                             // buf0 resident

  // ------------- layer 1: g = 0..12 (K padded to 416) ---------------------
  #pragma unroll
  for (int g = 0; g < NK1; ++g) {
    // issue next stages FIRST: latency hides under this step's compute
    {
      const unsigned short* np = (g < NK1 - 1)
          ? W1sw + (size_t)(g + 1) * CHUNK : W2sw;       // g==12 -> W2 chunk 0
      stage_w(np, bS + ((g + 1) & 1) * CHUNK, tid);
    }
    if (g < 11)
      stage_x(x, row0, g + 1,
              (unsigned short*)((char*)hS + ((g + 1) & 1) * 32768), tid);
    if (g == 11) {                                       // tail x values
      const float* px0 = x + (size_t)(row0 + w32 + m) * kDin;
      tl0 = (quad == 0) ? px0[384] : 0.f;
      tl1 = (quad == 0) ? px0[16 * kDin + 384] : 0.f;
    }

    s8v a0, a1;
    if (g < NK1 - 1) {
      const char* xb = (const char*)hS + (g & 1) * 32768;
      const char* rb0 = xb + (w32 + m) * 128;
      f4a c0 = *(const f4a*)(rb0 + u0);
      f4a c1 = *(const f4a*)(rb0 + (u0 ^ 16));
      const char* rb1 = rb0 + 2048;                      // +16 rows
      f4a c2 = *(const f4a*)(rb1 + u0);
      f4a c3 = *(const f4a*)(rb1 + (u0 ^ 16));
      s8u ua, ub;
      ua.u[0] = pk2(c0[0], c0[1]); ua.u[1] = pk2(c0[2], c0[3]);
      ua.u[2] = pk2(c1[0], c1[1]); ua.u[3] = pk2(c1[2], c1[3]);
      ub.u[0] = pk2(c2[0], c2[1]); ub.u[1] = pk2(c2[2], c2[3]);
      ub.u[2] = pk2(c3[0], c3[1]); ub.u[3] = pk2(c3[2], c3[3]);
      a0 = ua.s; a1 = ub.s;
    } else {                                 // only k==384 valid (quad0, j0)
      a0 = (s8v){0,0,0,0,0,0,0,0};
      a1 = (s8v){0,0,0,0,0,0,0,0};
      a0[0] = (short)f2bf(tl0);
      a1[0] = (short)f2bf(tl1);
    }

    const unsigned short* bB = bS + (g & 1) * CHUNK;
    #pragma unroll
    for (int t = 0; t < 12; ++t) {
      s8v b = *(const s8v*)&bB[(t * 64 + lane) * 8];
      accA[t] = __builtin_amdgcn_mfma_f32_16x16x32_bf16(a0, b, accA[t], 0, 0, 0);
      accB[t] = __builtin_amdgcn_mfma_f32_16x16x32_bf16(a1, b, accB[t], 0, 0, 0);
    }

    if (g == NK1 - 1) {
      // epilogue 1 (wave-private rows): bias + relu -> hS bf16
      // (xS region dead: last xS read was step 11, fenced by its barrier)
      #pragma unroll
      for (int t = 0; t < 12; ++t) {
        int c = t * 16 + m;
        float bb = b1[c];
        #pragma unroll
        for (int r4 = 0; r4 < 4; ++r4) {
          float v0 = accA[t][r4] + bb;
          hS[(w32 + quad * 4 + r4) * H2 + c] = f2bf(v0 > 0.f ? v0 : 0.f);
          float v1 = accB[t][r4] + bb;
          hS[(w32 + 16 + quad * 4 + r4) * H2 + c] = f2bf(v1 > 0.f ? v1 : 0.f);
          accA[t][r4] = 0.f;
          accB[t][r4] = 0.f;
        }
      }
    }
    __syncthreads();     // ONE barrier: drains stage(g+1); frees buf(g)
  }

  // ------------- layer 2: g = 13..18 (k2 = 0..5), parity continues --------
  #pragma unroll
  for (int k2 = 0; k2 < NK2; ++k2) {
    const int g = NK1 + k2;
    if (k2 < NK2 - 1)
      stage_w(W2sw + (size_t)(k2 + 1) * CHUNK,
              bS + ((g + 1) & 1) * CHUNK, tid);

    // A from hS: wave-private rows (fenced by barrier at end of g==12)
    s8v a0 = *(const s8v*)&hS[(w32 + m) * H2 + k2 * 32 + quad * 8];
    s8v a1 = *(const s8v*)&hS[(w32 + 16 + m) * H2 + k2 * 32 + quad * 8];
    const unsigned short* bB = bS + (g & 1) * CHUNK;
    #pragma unroll
    for (int t = 0; t < 12; ++t) {
      s8v b = *(const s8v*)&bB[(t * 64 + lane) * 8];
      accA[t] = __builtin_amdgcn_mfma_f32_16x16x32_bf16(a0, b, accA[t], 0, 0, 0);
      accB[t] = __builtin_amdgcn_mfma_f32_16x16x32_bf16(a1, b, accB[t], 0, 0, 0);
    }
    if (k2 < NK2 - 1) __syncthreads();       // drain stage; free buf(g)
  }

  // epilogue 2 (wave-private rows): bias + relu -> hS bf16
  #pragma unroll
  for (int t = 0; t < 12; ++t) {
    int c = t * 16 + m;
    float bb = b2[c];
    #pragma unroll
    for (int r4 = 0; r4 < 4; ++r4) {
      float v0 = accA[t][r4] + bb;
      hS[(w32 + quad * 4 + r4) * H2 + c] = f2bf(v0 > 0.f ? v0 : 0.f);
      float v1 = accB[t][r4] + bb;
      hS[(w32 + 16 + quad * 4 + r4) * H2 + c] = f2bf(v1 > 0.f ? v1 : 0.f);
    }
  }
  __syncthreads();                           // fence hS for the store reads

  // feat -> global, wave-private 32 rows, coalesced (12 x 16 B per lane)
  #pragma unroll
  for (int j = 0; j < 12; ++j) {
    int e = lane + j * 64;                   // 0..767 = 32 rows x 24 chunks
    int row = w32 + e / 24, c8 = e - (e / 24) * 24;
    *(s8v*)&featG[(size_t)(row0 + row) * kDh + c8 * 8] =
        *(const s8v*)&hS[row * H2 + c8 * 8];
  }
}

// ===========================================================================
//  BIG PATH head: register A-fragments from cache-resident featG
// ===========================================================================
__global__ __launch_bounds__(NT, 8)
void head_k(const int* __restrict__ qid, const int* __restrict__ isc,
            const float* __restrict__ Wh, const float* __restrict__ bh,
            const unsigned short* __restrict__ featG,
            const int* __restrict__ perm, float* __restrict__ out) {
  __shared__ int permS[BM];
  __shared__ int idxS[BM];

  const int tid  = threadIdx.x;
  const int lane = tid & 63, wid = tid >> 6;
  const int m = lane & 15, quad = lane >> 4;
  const int rh = wid >> 1, ch = wid & 1;
  const int row0 = blockIdx.x * BM;

  if (tid < BM) {
    int p = perm[row0 + tid];
    permS[tid] = p;
    idxS[tid] = qid[p] + isc[p] * kQ;
  }
  __syncthreads();

  const int w16 = rh * 16;
  const unsigned short* fp = featG + (size_t)permS[w16 + m] * kDh + quad * 8;
  s8v f[6];
  #pragma unroll
  for (int kk = 0; kk < 6; ++kk) f[kk] = *(const s8v*)(fp + kk * 32);

  const int hm = idxS[w16 + m];
  const s8v zf = (s8v){0,0,0,0,0,0,0,0};
  unsigned rem = 0xFFFFu;
  int runIdx = 0;
  while (rem) {
    int r0 = (int)__builtin_ctz(rem);
    int h = idxS[w16 + r0];                 // uniform (LDS broadcast)
    unsigned long long bal = __ballot(hm == h);
    unsigned mask16 = (unsigned)(bal & 0xFFFFu);
    rem &= ~mask16;
    if ((runIdx & 1) == ch) {               // parity-split runs across pair
      bool valid = (hm == h);
      const float* wq = Wh + ((size_t)h * kC + m) * kDh + quad * 8;
      f4v acch = (f4v){0.f, 0.f, 0.f, 0.f};
      #pragma unroll
      for (int kk = 0; kk < 6; ++kk) {
        float4 wlo = *(const float4*)(wq + kk * 32);
        float4 whi = *(const float4*)(wq + kk * 32 + 4);
        s8u ub;
        ub.u[0] = pk2(wlo.x, wlo.y);
        ub.u[1] = pk2(wlo.z, wlo.w);
        ub.u[2] = pk2(whi.x, whi.y);
        ub.u[3] = pk2(whi.z, whi.w);
        s8v afr = valid ? f[kk] : zf;
        acch = __builtin_amdgcn_mfma_f32_16x16x32_bf16(afr, ub.s, acch, 0, 0, 0);
      }
      float bhv = bh[(size_t)h * kC + m];
      #pragma unroll
      for (int reg = 0; reg < 4; ++reg) {
        int r = quad * 4 + reg;
        if ((mask16 >> r) & 1u)
          out[(size_t)permS[w16 + r] * kC + m] = acch[reg] + bhv;
      }
    }
    runIdx++;
  }
}

// ===========================================================================
//  FALLBACK: R8's proven fused kernel (perm-gathered x)
// ===========================================================================
__global__ __launch_bounds__(NT, 8)
void fused_qmlp8(const float* __restrict__ x,
                 const int*   __restrict__ qid,
                 const int*   __restrict__ isc,
                 const float* __restrict__ b1,
                 const float* __restrict__ b2,
                 const float* __restrict__ Wh,
                 const float* __restrict__ bh,
                 const unsigned short* __restrict__ W1sw,
                 const unsigned short* __restrict__ W2sw,
                 const int*   __restrict__ perm,
                 float* __restrict__ out) {
  __shared__ __align__(16) unsigned short hS[BM * H2];
  __shared__ __align__(16) unsigned short bS[CHUNK];
  __shared__ int permS[BM];
  __shared__ int idxS[BM];

  const int tid  = threadIdx.x;
  const int lane = tid & 63, wid = tid >> 6;
  const int m = lane & 15, quad = lane >> 4;
  const int rh = wid >> 1, ch = wid & 1;
  const int row0 = blockIdx.x * BM;

  {
    const char* g = (const char*)W1sw + (size_t)tid * 16;
    char* l = (char*)bS + ((tid >> 6) << 10);
    __builtin_amdgcn_global_load_lds((gas1_t)g, (las3_t)l, 16, 0, 0);
    if (tid < 256)
      __builtin_amdgcn_global_load_lds((gas1_t)(g + 8192), (las3_t)(l + 8192),
                                       16, 0, 0);
  }
  if (tid < BM) {
    int p = perm[row0 + tid];
    permS[tid] = p;
    idxS[tid] = qid[p] + isc[p] * kQ;
  }
  __syncthreads();

  const float* px = x + (size_t)permS[rh * 16 + m] * kDin;

  f4v acc[6];
  #pragma unroll
  for (int t = 0; t < 6; ++t) acc[t] = (f4v){0.f, 0.f, 0.f, 0.f};

  f4a c0 = *(const f4a*)(px + quad * 8);
  f4a c1 = *(const f4a*)(px + quad * 8 + 4);
  float tl = 0.f;

  #pragma unroll
  for (int kk = 0; kk < NK1; ++kk) {
    s8v a;
    if (kk < NK1 - 1) {
      s8u ua;
      ua.u[0] = pk2(c0[0], c0[1]); ua.u[1] = pk2(c0[2], c0[3]);
      ua.u[2] = pk2(c1[0], c1[1]); ua.u[3] = pk2(c1[2], c1[3]);
      a = ua.s;
    } else {
      a = (s8v){0,0,0,0,0,0,0,0};
      a[0] = (short)f2bf(tl);
    }

    #pragma unroll
    for (int t = 0; t < 6; ++t) {
      s8v b = *(const s8v*)&bS[((ch * 6 + t) * 64 + lane) * 8];
      acc[t] = __builtin_amdgcn_mfma_f32_16x16x32_bf16(a, b, acc[t], 0, 0, 0);
    }
    __syncthreads();

    {
      const unsigned short* np = (kk < NK1 - 1)
          ? W1sw + (size_t)(kk + 1) * CHUNK : W2sw;
      const char* g = (const char*)np + (size_t)tid * 16;
      char* l = (char*)bS + ((tid >> 6) << 10);
      __builtin_amdgcn_global_load_lds((gas1_t)g, (las3_t)l, 16, 0, 0);
      if (tid < 256)
        __builtin_amdgcn_global_load_lds((gas1_t)(g + 8192), (las3_t)(l + 8192),
                                         16, 0, 0);
    }
    if (kk < NK1 - 2) {
      c0 = *(const f4a*)(px + (kk + 1) * 32 + quad * 8);
      c1 = *(const f4a*)(px + (kk + 1) * 32 + quad * 8 + 4);
    } else if (kk == NK1 - 2) {
      tl = (quad == 0) ? px[384] : 0.f;
    }
    if (kk == NK1 - 1) {
      #pragma unroll
      for (int t = 0; t < 6; ++t) {
        int c = ch * 96 + t * 16 + m;
        float bb = b1[c];
        #pragma unroll
        for (int r4 = 0; r4 < 4; ++r4) {
          int r = rh * 16 + quad * 4 + r4;
          float v0 = acc[t][r4] + bb;
          hS[r * H2 + c] = f2bf(v0 > 0.f ? v0 : 0.f);
          acc[t][r4] = 0.f;
        }
      }
    }
    __syncthreads();
  }

  const int ar0 = (rh * 16 + m) * H2;
  #pragma unroll
  for (int k2 = 0; k2 < NK2; ++k2) {
    s8v a = *(const s8v*)&hS[ar0 + k2 * 32 + quad * 8];
    #pragma unroll
    for (int t = 0; t < 6; ++t) {
      s8v b = *(const s8v*)&bS[((ch * 6 + t) * 64 + lane) * 8];
      acc[t] = __builtin_amdgcn_mfma_f32_16x16x32_bf16(a, b, acc[t], 0, 0, 0);
    }
    __syncthreads();
    if (k2 < NK2 - 1) {
      const char* g = (const char*)(W2sw + (size_t)(k2 + 1) * CHUNK)
                    + (size_t)tid * 16;
      char* l = (char*)bS + ((tid >> 6) << 10);
      __builtin_amdgcn_global_load_lds((gas1_t)g, (las3_t)l, 16, 0, 0);
      if (tid < 256)
        __builtin_amdgcn_global_load_lds((gas1_t)(g + 8192), (las3_t)(l + 8192),
                                         16, 0, 0);
    } else {
      #pragma unroll
      for (int t = 0; t < 6; ++t) {
        int c = ch * 96 + t * 16 + m;
        float bb = b2[c];
        #pragma unroll
        for (int r4 = 0; r4 < 4; ++r4) {
          int r = rh * 16 + quad * 4 + r4;
          float v0 = acc[t][r4] + bb;
          hS[r * H2 + c] = f2bf(v0 > 0.f ? v0 : 0.f);
        }
      }
    }
    __syncthreads();
  }

  {
    const int w16 = rh * 16;
    const int hm = idxS[w16 + m];
    unsigned rem = 0xFFFFu;
    int runIdx = 0;
    while (rem) {
      int r0 = (int)__builtin_ctz(rem);
      int h = idxS[w16 + r0];
      unsigned long long bal = __ballot(hm == h);
      unsigned mask16 = (unsigned)(bal & 0xFFFFu);
      rem &= ~mask16;
      if ((runIdx & 1) == ch) {
        const float* wq = Wh + ((size_t)h * kC + m) * kDh + quad * 8;
        f4v acch = (f4v){0.f, 0.f, 0.f, 0.f};
        #pragma unroll
        for (int kk = 0; kk < 6; ++kk) {
          float4 wlo = *(const float4*)(wq + kk * 32);
          float4 whi = *(const float4*)(wq + kk * 32 + 4);
          s8u ub;
          ub.u[0] = pk2(wlo.x, wlo.y);
          ub.u[1] = pk2(wlo.z, wlo.w);
          ub.u[2] = pk2(whi.x, whi.y);
          ub.u[3] = pk2(whi.z, whi.w);
          s8v afr = *(const s8v*)&hS[(w16 + m) * H2 + kk * 32 + quad * 8];
          if (hm != h) afr = (s8v){0,0,0,0,0,0,0,0};
          acch = __builtin_amdgcn_mfma_f32_16x16x32_bf16(afr, ub.s, acch, 0, 0, 0);
        }
        float bhv = bh[(size_t)h * kC + m];
        #pragma unroll
        for (int reg = 0; reg < 4; ++reg) {
          int r = quad * 4 + reg;
          if ((mask16 >> r) & 1u)
            out[(size_t)permS[w16 + r] * kC + m] = acch[reg] + bhv;
        }
      }
      runIdx++;
    }
  }
}

extern "C" void kernel_launch(void* const* d_in, const int* in_sizes, int n_in,
                              void* d_out, int out_size, void* d_ws, size_t ws_size,
                              hipStream_t stream) {
  const float* x  = (const float*)d_in[0];
  const int*   qd = (const int*)  d_in[1];
  const int*   ic = (const int*)  d_in[2];
  const float* W1 = (const float*)d_in[3];
  const float* b1 = (const float*)d_in[4];
  const float* W2 = (const float*)d_in[5];
  const float* b2 = (const float*)d_in[6];
  const float* Wh = (const float*)d_in[7];
  const float* bh = (const float*)d_in[8];
  float* out = (float*)d_out;

  char* ws = (char*)d_ws;
  int B = in_sizes[1];   // 131072
  int nbH = (B + 255) / 256;

  const bool big = (d_ws != nullptr) && (ws_size >= WB_NEED)
                 && (ws_size < WS_SANE_MAX);

  if (big) {
    // ---- big path: pipelined trunk + head ----
    unsigned short* featG = (unsigned short*)(ws + WB_FEAT);
    unsigned short* W1sw  = (unsigned short*)(ws + WB_W1);
    unsigned short* W2sw  = (unsigned short*)(ws + WB_W2);
    int* hist = (int*)(ws + WB_HIST);
    int* rank = (int*)(ws + WB_CUR);
    int* perm = (int*)(ws + WB_PERM);

    hipMemsetAsync(hist, 0, 4096 * sizeof(int), stream);
    combo_prep<<<nbH + 312 + 144, 256, 0, stream>>>(qd, ic, B, nbH, W1, W2,
                                                    hist, W1sw, W2sw);
    scatter2<<<(B + 255) / 256, 256, 0, stream>>>(qd, ic, B, hist, rank, perm);
    trunk_k4<<<B / BM2, NT, 0, stream>>>(x, b1, b2, W1sw, W2sw, featG);
    head_k<<<B / BM, NT, 0, stream>>>(qd, ic, Wh, bh, featG, perm, out);
  } else {
    // ---- fallback: proven R8 single fused kernel ----
    unsigned short* W1sw = (unsigned short*)(ws + WS_W1);
    unsigned short* W2sw = (unsigned short*)(ws + WS_W2);
    int* hist = (int*)(ws + WS_HIST);
    int* rank = (int*)(ws + WS_CUR);
    int* perm = (int*)(ws + WS_PERM);

    hipMemsetAsync(hist, 0, 4096 * sizeof(int), stream);
    combo_prep<<<nbH + 312 + 144, 256, 0, stream>>>(qd, ic, B, nbH, W1, W2,
                                                    hist, W1sw, W2sw);
    scatter2<<<(B + 255) / 256, 256, 0, stream>>>(qd, ic, B, hist, rank, perm);
    fused_qmlp8<<<B / BM, NT, 0, stream>>>(x, qd, ic, b1, b2, Wh, bh,
                                           W1sw, W2sw, perm, out);
  }
}